// Round 11
// baseline (3351.130 us; speedup 1.0000x reference)
//
#include <hip/hip_runtime.h>

typedef __attribute__((ext_vector_type(4))) float f32x4;
typedef __attribute__((ext_vector_type(4))) unsigned int u32x4;
typedef __attribute__((ext_vector_type(4))) int i32x4;
typedef __attribute__((ext_vector_type(8))) int i32x8;
typedef unsigned char u8;
typedef unsigned short u16;
typedef unsigned int u32;

#define MBYTE (1024*1024)
#define TTOK 16384
#define HDIM 4096

// Interleaved operand layout (A and B both produced by our kernels):
// row-major 4096B rows of 32 K-tiles x 128B; within a tile, chunk c = p*4+q4
// (16B) holds lane-fragment bytes for (p, q4). K-permutation identical for A
// and B, so any self-consistent HW K-mapping gives the same dot product
// (HW scales fed as 1.0).

__device__ __forceinline__ void gload_lds16(const void* g, void* l) {
  __builtin_amdgcn_global_load_lds((const __attribute__((address_space(1))) void*)g,
                                   (__attribute__((address_space(3))) void*)l, 16, 0, 0);
}

// ---- weight convert + transpose: W[k][n] f32 -> WT[n][k-interleaved] fp8 ----
__global__ __launch_bounds__(256) void k_wconv(const float* __restrict__ w0,
                                               const float* __restrict__ w1,
                                               const float* __restrict__ w2,
                                               u8* __restrict__ out) {
  __shared__ float tl[64][68];
  const int tid = threadIdx.x;
  const int bn = blockIdx.x, bk = blockIdx.y, z = blockIdx.z;
  const float* W = (z == 0) ? w0 : (z == 1 ? w1 : w2);
  u8* o = out + (size_t)z * 16 * MBYTE;
#pragma unroll
  for (int it = 0; it < 4; ++it) {
    int idx = it * 256 + tid;
    int r = idx >> 4, c4 = idx & 15;
    f32x4 v = *(const f32x4*)(W + (size_t)(bk * 64 + r) * HDIM + bn * 64 + c4 * 4);
    *(f32x4*)&tl[r][c4 * 4] = v;
  }
  __syncthreads();
  {
    int n = tid >> 2, q4 = tid & 3;
    u32 dw[4];
#pragma unroll
    for (int d = 0; d < 4; ++d) {
      int k0 = (d >> 1) * 32 + q4 * 8 + (d & 1) * 4;
      int w = __builtin_amdgcn_cvt_pk_fp8_f32(tl[k0 + 0][n], tl[k0 + 1][n], 0, false);
      w = __builtin_amdgcn_cvt_pk_fp8_f32(tl[k0 + 2][n], tl[k0 + 3][n], w, true);
      dw[d] = (u32)w;
    }
    u32x4 pack = {dw[0], dw[1], dw[2], dw[3]};
    *(u32x4*)(o + (size_t)(bn * 64 + n) * HDIM + (bk >> 1) * 128 + (bk & 1) * 64 + q4 * 16) = pack;
  }
}

// ---- fused elementwise: MODE 0: relu+rms+quant; 1: add+rms+quant; 2: add+rms->yout ----
// Group scale is rounded to bf16 FIRST, then used for quantization -> GEMM's
// bf16 dequant scale cancels exactly (no extra numeric error).
template <int MODE>
__global__ __launch_bounds__(256) void k_norm(const float* __restrict__ in,
                                              float* __restrict__ resid,
                                              const float* __restrict__ nw,
                                              u32* __restrict__ qout,
                                              u16* __restrict__ asct,
                                              float* __restrict__ yout) {
  const int row = blockIdx.x, t = threadIdx.x;
  const size_t base = (size_t)row * HDIM;
  const f32x4* inr = (const f32x4*)(in + base);
  f32x4* residr = (f32x4*)(resid + base);
  f32x4 v[4];
  float ss = 0.f;
#pragma unroll
  for (int j = 0; j < 4; ++j) {
    f32x4 a = inr[j * 256 + t];
    if (MODE == 0) {
      a.x = fmaxf(a.x, 0.f); a.y = fmaxf(a.y, 0.f);
      a.z = fmaxf(a.z, 0.f); a.w = fmaxf(a.w, 0.f);
    } else {
      f32x4 rz = residr[j * 256 + t];
      a.x += rz.x; a.y += rz.y; a.z += rz.z; a.w += rz.w;
    }
    if (MODE < 2) residr[j * 256 + t] = a;
    v[j] = a;
    ss += a.x * a.x + a.y * a.y + a.z * a.z + a.w * a.w;
  }
#pragma unroll
  for (int m = 1; m <= 32; m <<= 1) ss += __shfl_xor(ss, m, 64);
  __shared__ float sred[4];
  if ((t & 63) == 0) sred[t >> 6] = ss;
  __syncthreads();
  float tot = sred[0] + sred[1] + sred[2] + sred[3];
  float rinv = rsqrtf(tot * (1.f / (float)HDIM) + 1e-6f);
#pragma unroll
  for (int j = 0; j < 4; ++j) {
    f32x4 nv = ((const f32x4*)nw)[j * 256 + t];
    f32x4 y;
    y.x = v[j].x * rinv * nv.x; y.y = v[j].y * rinv * nv.y;
    y.z = v[j].z * rinv * nv.z; y.w = v[j].w * rinv * nv.w;
    if (MODE == 2) {
      ((f32x4*)yout)[(size_t)row * 1024 + j * 256 + t] = y;
    } else {
      float am = fmaxf(fmaxf(fabsf(y.x), fabsf(y.y)), fmaxf(fabsf(y.z), fabsf(y.w)));
#pragma unroll
      for (int m = 1; m <= 16; m <<= 1) am = fmaxf(am, __shfl_xor(am, m, 64));
      am = fmaxf(am, 1e-12f);
      float s = am * (1.f / 448.f);
      u32 x = __float_as_uint(s);
      u32 rb = (x + 0x7FFFu + ((x >> 16) & 1u)) >> 16;     // RNE to bf16
      float sbf = __uint_as_float(rb << 16);
      float inv = 1.0f / sbf;
      int d = __builtin_amdgcn_cvt_pk_fp8_f32(y.x * inv, y.y * inv, 0, false);
      d = __builtin_amdgcn_cvt_pk_fp8_f32(y.z * inv, y.w * inv, d, true);
      // interleaved layout: permute u32 index within each 32-u32 (128B) K-tile
      int k4 = j * 256 + t;
      int k4w = k4 & 31;
      int k4n = (k4 & ~31) | (((k4w >> 4) & 1) << 4) | (((k4w >> 1) & 3) << 2)
              | (((k4w >> 3) & 1) << 1) | (k4w & 1);
      qout[(size_t)row * 1024 + k4n] = (u32)d;
      if ((t & 31) == 0) asct[(size_t)(j * 8 + (t >> 5)) * TTOK + row] = (u16)rb;
    }
  }
}

// ---- fp8 block-scaled GEMM, 128x128 tile, 4 waves (64x64), BK=128, MX-rate MFMA.
// B staged via LDS (dbuf, swizzled, gload_lds); A-fragments loaded DIRECTLY from
// global into registers (double-buffered aA/aB, prefetch distance 1 kt), served
// by L1/L2 (per-kt A slice = 16KB, L1-resident; panel L2-hot via XCD swizzle).
// One s_barrier + one vmcnt(0) drain per kt; drained loads were issued a full
// body (~1500 cyc) earlier.
__global__ __launch_bounds__(256, 2) void k_gemm(const u8* __restrict__ A,    // [T][4096] fp8 interleaved
                                                 const u8* __restrict__ B,    // [4096][4096] fp8 interleaved
                                                 const u16* __restrict__ aSb, // [32][T] bf16 scales
                                                 const float* __restrict__ bS, // [32][32]
                                                 float* __restrict__ C) {      // [T][4096]
  __shared__ u8 Bl[2][128 * 128];   // 32KB
  __shared__ u8 AsB[32 * 128 * 2];  // 8KB bf16 act scales [kt][row]
  const int tid = threadIdx.x;
  const int lane = tid & 63, wave = tid >> 6;
  // bijective XCD swizzle: 4096 blocks, 8 XCDs, 512 per chunk (bn fast -> A-panel reuse)
  const int lin = blockIdx.x;
  const int swzb = (lin & 7) * 512 + (lin >> 3);
  const int bn = swzb & 31, bm = swzb >> 5;
  const int brow = bm * 128, bcol = bn * 128;
  const int wrb = (wave >> 1) * 64, wcb = (wave & 1) * 64;   // 64x64 wave tile
  const int r16 = lane & 15, q4 = lane >> 4;
  const int swz3 = r16 & 7;
  const int c0 = (q4 ^ swz3) << 4;
  const int c1 = ((4 + q4) ^ swz3) << 4;

  // B staging: pass i covers rows i*32 + (tid>>3), chunk (tid&7), inverse-swizzled src
  const int srow = tid >> 3;
  const int sc = ((tid & 7) ^ (srow & 7)) << 4;
  const u8* bP = B + (size_t)(bcol + srow) * HDIM + sc;
  const int ldst = tid * 16;

#define BSTAGE(c, kt) do {                                                      \
    _Pragma("unroll")                                                           \
    for (int i = 0; i < 4; ++i)                                                 \
      gload_lds16(bP + (size_t)(kt) * 128 + (size_t)i * 32 * HDIM,              \
                  &Bl[c][i * 4096 + ldst]);                                     \
  } while (0)

  // A direct-fragment base: lane (r16,q4) reads row*4096 + kt*128 + q4*16 (+64)
  const u8* aD = A + (size_t)(brow + wrb + r16) * HDIM + q4 * 16;

#define APREF(R, kt) do {                                                       \
    _Pragma("unroll")                                                           \
    for (int m = 0; m < 4; ++m) {                                               \
      const u8* p_ = aD + (size_t)m * 16 * HDIM + (size_t)(kt) * 128;           \
      R[2 * m]     = *(const i32x4*)(p_);                                       \
      R[2 * m + 1] = *(const i32x4*)(p_ + 64);                                  \
    }                                                                           \
  } while (0)

  // prologue: As (8KB) into LDS, B tiles 0,1 staged, A-frags kt=0 into regs
  {
    const u8* asrc = (const u8*)aSb;
#pragma unroll
    for (int j = 0; j < 2; ++j) {
      int ch = j * 256 + tid;
      gload_lds16(asrc + (size_t)(ch >> 4) * (TTOK * 2) + (size_t)brow * 2 + (ch & 15) * 16,
                  &AsB[j * 4096 + ldst]);
    }
  }
  BSTAGE(0, 0);
  BSTAGE(1, 1);
  i32x4 aA[8], aB[8];
  APREF(aA, 0);

  f32x4 accm[4][4] = {};
  const f32x4 z4 = {0.f, 0.f, 0.f, 0.f};

#define BODY(KT, AC, AN) do {                                                   \
    const int cur_ = (KT) & 1;                                                  \
    asm volatile("s_waitcnt vmcnt(0)" ::: "memory");                            \
    __builtin_amdgcn_s_barrier();                                               \
    __builtin_amdgcn_sched_barrier(0);                                          \
    i32x4 blo[4], bhi[4];                                                       \
    _Pragma("unroll")                                                           \
    for (int n = 0; n < 4; ++n) {                                               \
      const u8* rp = &Bl[cur_][(wcb + n * 16 + r16) * 128];                     \
      blo[n] = *(const i32x4*)(rp + c0);                                        \
      bhi[n] = *(const i32x4*)(rp + c1);                                        \
    }                                                                           \
    if ((KT) < 31) { BSTAGE(cur_ ^ 1, (KT) + 1); APREF(AN, (KT) + 1); }         \
    __builtin_amdgcn_sched_barrier(0);                                          \
    const float wsb = bS[(KT) * 32 + bn];                                       \
    i32x8 bfr[4];                                                               \
    _Pragma("unroll")                                                           \
    for (int n = 0; n < 4; ++n)                                                 \
      bfr[n] = __builtin_shufflevector(blo[n], bhi[n], 0, 1, 2, 3, 4, 5, 6, 7); \
    _Pragma("unroll")                                                           \
    for (int m = 0; m < 4; ++m) {                                               \
      i32x8 afr = __builtin_shufflevector(AC[2 * m], AC[2 * m + 1],             \
                                          0, 1, 2, 3, 4, 5, 6, 7);              \
      const u32* spp = (const u32*)&AsB[(KT) * 256 + (wrb + m * 16 + q4 * 4) * 2]; \
      u32 sp0 = spp[0], sp1 = spp[1];                                           \
      f32x4 sa;                                                                 \
      sa.x = __uint_as_float(sp0 << 16);                                        \
      sa.y = __uint_as_float(sp0 & 0xFFFF0000u);                                \
      sa.z = __uint_as_float(sp1 << 16);                                        \
      sa.w = __uint_as_float(sp1 & 0xFFFF0000u);                                \
      const f32x4 s = sa * wsb;                                                 \
      f32x4 acc[4];                                                             \
      __builtin_amdgcn_s_setprio(1);                                            \
      _Pragma("unroll")                                                         \
      for (int n = 0; n < 4; ++n)                                               \
        acc[n] = __builtin_amdgcn_mfma_scale_f32_16x16x128_f8f6f4(              \
            afr, bfr[n], z4, 0, 0, 0, 0x7F7F7F7F, 0, 0x7F7F7F7F);               \
      __builtin_amdgcn_s_setprio(0);                                            \
      _Pragma("unroll")                                                         \
      for (int n = 0; n < 4; ++n) accm[m][n] += acc[n] * s;                     \
    }                                                                           \
  } while (0)

#pragma unroll 1
  for (int kt2 = 0; kt2 < 16; ++kt2) {
    BODY(kt2 * 2,     aA, aB);
    BODY(kt2 * 2 + 1, aB, aA);
  }
#undef BODY
#undef APREF
#undef BSTAGE

#pragma unroll
  for (int m = 0; m < 4; ++m) {
#pragma unroll
    for (int r = 0; r < 4; ++r) {
      float* Cp = C + (size_t)(brow + wrb + m * 16 + q4 * 4 + r) * HDIM + bcol + wcb + r16;
#pragma unroll
      for (int n = 0; n < 4; ++n) Cp[n * 16] = accm[m][n][r];
    }
  }
}

extern "C" void kernel_launch(void* const* d_in, const int* in_sizes, int n_in,
                              void* d_out, int out_size, void* d_ws, size_t ws_size,
                              hipStream_t stream) {
  const float* x  = (const float*)d_in[0];
  const float* nw = (const float*)d_in[1];
  const float* w0 = (const float*)d_in[2];
  const float* w1 = (const float*)d_in[3];
  const float* w2 = (const float*)d_in[4];
  const float* s0 = (const float*)d_in[5];
  const float* s1 = (const float*)d_in[6];
  const float* s2 = (const float*)d_in[7];
  float* out = (float*)d_out;
  char* ws = (char*)d_ws;

  u8*  wqt   = (u8*)ws;                               // 3 x 16MB
  u32* q     = (u32*)(ws + (size_t)48 * MBYTE);       // 64MB fp8 activations
  u16* asc   = (u16*)(ws + (size_t)112 * MBYTE);      // 1MB  [32][T] bf16
  float* rsd = (float*)(ws + (size_t)114 * MBYTE);    // 256MB residual

  k_wconv<<<dim3(64, 64, 3), 256, 0, stream>>>(w0, w1, w2, wqt);

  k_norm<0><<<TTOK, 256, 0, stream>>>(x, rsd, nw, q, asc, nullptr);
  k_gemm<<<4096, 256, 0, stream>>>((const u8*)q, wqt, asc, s0, out);

  k_norm<1><<<TTOK, 256, 0, stream>>>(out, rsd, nw + HDIM, q, asc, nullptr);
  k_gemm<<<4096, 256, 0, stream>>>((const u8*)q, wqt + (size_t)16 * MBYTE, asc, s1, out);

  k_norm<1><<<TTOK, 256, 0, stream>>>(out, rsd, nw + 2 * HDIM, q, asc, nullptr);
  k_gemm<<<4096, 256, 0, stream>>>((const u8*)q, wqt + (size_t)32 * MBYTE, asc, s2, out);

  k_norm<2><<<TTOK, 256, 0, stream>>>(out, rsd, nw + 3 * HDIM, nullptr, nullptr, out);
}

// Round 12
// 2920.881 us; speedup vs baseline: 1.1473x; 1.1473x over previous
//
#include <hip/hip_runtime.h>

typedef __attribute__((ext_vector_type(4))) float f32x4;
typedef __attribute__((ext_vector_type(4))) unsigned int u32x4;
typedef __attribute__((ext_vector_type(4))) int i32x4;
typedef __attribute__((ext_vector_type(8))) int i32x8;
typedef unsigned char u8;
typedef unsigned short u16;
typedef unsigned int u32;

#define MBYTE (1024*1024)
#define TTOK 16384
#define HDIM 4096

// Interleaved operand layout (A and B both produced by our kernels):
// row-major 4096B rows of 32 K-tiles x 128B; within a tile, chunk c = p*4+q4
// (16B) holds lane (.,q4)'s fragment bytes for half p. K-permutation identical
// for A and B -> any self-consistent HW K-mapping gives the same dot product
// (HW scales fed as 1.0).

__device__ __forceinline__ void gload_lds16(const void* g, void* l) {
  __builtin_amdgcn_global_load_lds((const __attribute__((address_space(1))) void*)g,
                                   (__attribute__((address_space(3))) void*)l, 16, 0, 0);
}

// ---- weight convert + transpose: W[k][n] f32 -> WT[n][k-interleaved] fp8 ----
__global__ __launch_bounds__(256) void k_wconv(const float* __restrict__ w0,
                                               const float* __restrict__ w1,
                                               const float* __restrict__ w2,
                                               u8* __restrict__ out) {
  __shared__ float tl[64][68];
  const int tid = threadIdx.x;
  const int bn = blockIdx.x, bk = blockIdx.y, z = blockIdx.z;
  const float* W = (z == 0) ? w0 : (z == 1 ? w1 : w2);
  u8* o = out + (size_t)z * 16 * MBYTE;
#pragma unroll
  for (int it = 0; it < 4; ++it) {
    int idx = it * 256 + tid;
    int r = idx >> 4, c4 = idx & 15;
    f32x4 v = *(const f32x4*)(W + (size_t)(bk * 64 + r) * HDIM + bn * 64 + c4 * 4);
    *(f32x4*)&tl[r][c4 * 4] = v;
  }
  __syncthreads();
  {
    int n = tid >> 2, q4 = tid & 3;
    u32 dw[4];
#pragma unroll
    for (int d = 0; d < 4; ++d) {
      int k0 = (d >> 1) * 32 + q4 * 8 + (d & 1) * 4;
      int w = __builtin_amdgcn_cvt_pk_fp8_f32(tl[k0 + 0][n], tl[k0 + 1][n], 0, false);
      w = __builtin_amdgcn_cvt_pk_fp8_f32(tl[k0 + 2][n], tl[k0 + 3][n], w, true);
      dw[d] = (u32)w;
    }
    u32x4 pack = {dw[0], dw[1], dw[2], dw[3]};
    *(u32x4*)(o + (size_t)(bn * 64 + n) * HDIM + (bk >> 1) * 128 + (bk & 1) * 64 + q4 * 16) = pack;
  }
}

// ---- fused elementwise: MODE 0: relu+rms+quant; 1: add+rms+quant; 2: add+rms->yout ----
// Group scale is rounded to bf16 FIRST, then used for quantization -> GEMM's
// bf16 dequant scale cancels exactly.
template <int MODE>
__global__ __launch_bounds__(256) void k_norm(const float* __restrict__ in,
                                              float* __restrict__ resid,
                                              const float* __restrict__ nw,
                                              u32* __restrict__ qout,
                                              u16* __restrict__ asct,
                                              float* __restrict__ yout) {
  const int row = blockIdx.x, t = threadIdx.x;
  const size_t base = (size_t)row * HDIM;
  const f32x4* inr = (const f32x4*)(in + base);
  f32x4* residr = (f32x4*)(resid + base);
  f32x4 v[4];
  float ss = 0.f;
#pragma unroll
  for (int j = 0; j < 4; ++j) {
    f32x4 a = inr[j * 256 + t];
    if (MODE == 0) {
      a.x = fmaxf(a.x, 0.f); a.y = fmaxf(a.y, 0.f);
      a.z = fmaxf(a.z, 0.f); a.w = fmaxf(a.w, 0.f);
    } else {
      f32x4 rz = residr[j * 256 + t];
      a.x += rz.x; a.y += rz.y; a.z += rz.z; a.w += rz.w;
    }
    if (MODE < 2) residr[j * 256 + t] = a;
    v[j] = a;
    ss += a.x * a.x + a.y * a.y + a.z * a.z + a.w * a.w;
  }
#pragma unroll
  for (int m = 1; m <= 32; m <<= 1) ss += __shfl_xor(ss, m, 64);
  __shared__ float sred[4];
  if ((t & 63) == 0) sred[t >> 6] = ss;
  __syncthreads();
  float tot = sred[0] + sred[1] + sred[2] + sred[3];
  float rinv = rsqrtf(tot * (1.f / (float)HDIM) + 1e-6f);
#pragma unroll
  for (int j = 0; j < 4; ++j) {
    f32x4 nv = ((const f32x4*)nw)[j * 256 + t];
    f32x4 y;
    y.x = v[j].x * rinv * nv.x; y.y = v[j].y * rinv * nv.y;
    y.z = v[j].z * rinv * nv.z; y.w = v[j].w * rinv * nv.w;
    if (MODE == 2) {
      ((f32x4*)yout)[(size_t)row * 1024 + j * 256 + t] = y;
    } else {
      float am = fmaxf(fmaxf(fabsf(y.x), fabsf(y.y)), fmaxf(fabsf(y.z), fabsf(y.w)));
#pragma unroll
      for (int m = 1; m <= 16; m <<= 1) am = fmaxf(am, __shfl_xor(am, m, 64));
      am = fmaxf(am, 1e-12f);
      float s = am * (1.f / 448.f);
      u32 x = __float_as_uint(s);
      u32 rb = (x + 0x7FFFu + ((x >> 16) & 1u)) >> 16;     // RNE to bf16
      float sbf = __uint_as_float(rb << 16);
      float inv = 1.0f / sbf;
      int d = __builtin_amdgcn_cvt_pk_fp8_f32(y.x * inv, y.y * inv, 0, false);
      d = __builtin_amdgcn_cvt_pk_fp8_f32(y.z * inv, y.w * inv, d, true);
      int k4 = j * 256 + t;
      int k4w = k4 & 31;
      int k4n = (k4 & ~31) | (((k4w >> 4) & 1) << 4) | (((k4w >> 1) & 3) << 2)
              | (((k4w >> 3) & 1) << 1) | (k4w & 1);
      qout[(size_t)row * 1024 + k4n] = (u32)d;
      if ((t & 31) == 0) asct[(size_t)(j * 8 + (t >> 5)) * TTOK + row] = (u16)rb;
    }
  }
}

// ---- fp8 block-scaled GEMM, 128x128 tile, 4 waves (64x64), BK=128, MX-rate MFMA.
// B via LDS (3 buffers, swizzled gload_lds); A-fragments DIRECT from global into
// regs (dbuf aA/aB; raw chunks q4*16 / +64, 16 full 64B segments per load).
// Body kt issues APREF(kt+1) then BSTAGE(kt+2); top-of-body s_waitcnt vmcnt(4)
// retires A(kt) (1-body lead) + B(kt) (2-body lead), leaves B(kt+1) in flight.
// ONE s_barrier per kt (3-buffer hazard-free). waves_per_eu(2,2) pins VGPR<=256.
__global__ __launch_bounds__(256)
__attribute__((amdgpu_waves_per_eu(2, 2)))
void k_gemm(const u8* __restrict__ A,     // [T][4096] fp8 interleaved
            const u8* __restrict__ B,     // [4096][4096] fp8 interleaved
            const u16* __restrict__ aSb,  // [32][T] bf16 scales
            const float* __restrict__ bS, // [32][32]
            float* __restrict__ C) {      // [T][4096]
  __shared__ u8 Bl[3][128 * 128];   // 48KB
  __shared__ u8 AsB[32 * 128 * 2];  // 8KB bf16 act scales [kt][row]
  const int tid = threadIdx.x;
  const int lane = tid & 63, wave = tid >> 6;
  // bijective XCD swizzle: 4096 blocks, 8 XCDs, 512 per chunk (bn fast -> A-panel L2 reuse)
  const int lin = blockIdx.x;
  const int swzb = (lin & 7) * 512 + (lin >> 3);
  const int bn = swzb & 31, bm = swzb >> 5;
  const int brow = bm * 128, bcol = bn * 128;
  const int wrb = (wave >> 1) * 64, wcb = (wave & 1) * 64;   // 64x64 wave tile
  const int r16 = lane & 15, q4 = lane >> 4;
  const int swz3 = r16 & 7;
  const int c0 = (q4 ^ swz3) << 4;
  const int c1 = ((4 + q4) ^ swz3) << 4;

  // B staging: pass i covers rows i*32 + (tid>>3), chunk (tid&7), inverse-swizzled src
  const int srow = tid >> 3;
  const int sc = ((tid & 7) ^ (srow & 7)) << 4;
  const u8* bP = B + (size_t)(bcol + srow) * HDIM + sc;
  const int ldst = tid * 16;

#define BSTAGE(bi, kt) do {                                                     \
    _Pragma("unroll")                                                           \
    for (int i = 0; i < 4; ++i)                                                 \
      gload_lds16(bP + (size_t)(kt) * 128 + (size_t)i * 32 * HDIM,              \
                  &Bl[bi][i * 4096 + ldst]);                                    \
  } while (0)

  // A direct-fragment base: lane (r16,q4), row-block m -> raw chunks q4*16, +64
  const u8* aD = A + (size_t)(brow + wrb + r16) * HDIM + q4 * 16;

#define APREF(R, kt) do {                                                       \
    _Pragma("unroll")                                                           \
    for (int m = 0; m < 4; ++m) {                                               \
      const u8* p_ = aD + (size_t)m * 16 * HDIM + (size_t)(kt) * 128;           \
      R[2 * m]     = *(const i32x4*)(p_);                                       \
      R[2 * m + 1] = *(const i32x4*)(p_ + 64);                                  \
    }                                                                           \
  } while (0)

  // prologue: As (8KB) -> LDS (oldest in FIFO), then B0, A0, B1
  {
    const u8* asrc = (const u8*)aSb;
#pragma unroll
    for (int j = 0; j < 2; ++j) {
      int ch = j * 256 + tid;
      gload_lds16(asrc + (size_t)(ch >> 4) * (TTOK * 2) + (size_t)brow * 2 + (ch & 15) * 16,
                  &AsB[j * 4096 + ldst]);
    }
  }
  i32x4 aA[8], aB[8];
  BSTAGE(0, 0);
  APREF(aA, 0);
  BSTAGE(1, 1);

  f32x4 accm[4][4] = {};
  const f32x4 z4 = {0.f, 0.f, 0.f, 0.f};

#define BODY(KT, AC, AN) do {                                                   \
    const int cur_ = (KT) % 3;                                                  \
    if ((KT) < 31) asm volatile("s_waitcnt vmcnt(4)" ::: "memory");             \
    else           asm volatile("s_waitcnt vmcnt(0)" ::: "memory");             \
    __builtin_amdgcn_s_barrier();                                               \
    __builtin_amdgcn_sched_barrier(0);                                          \
    i32x4 blo[4], bhi[4];                                                       \
    _Pragma("unroll")                                                           \
    for (int n = 0; n < 4; ++n) {                                               \
      const u8* rp = &Bl[cur_][(wcb + n * 16 + r16) * 128];                     \
      blo[n] = *(const i32x4*)(rp + c0);                                        \
      bhi[n] = *(const i32x4*)(rp + c1);                                        \
    }                                                                           \
    if ((KT) < 31) APREF(AN, (KT) + 1);                                         \
    if ((KT) < 30) BSTAGE(((KT) + 2) % 3, (KT) + 2);                            \
    const float wsb = bS[(KT) * 32 + bn];                                       \
    i32x8 bfr[4];                                                               \
    _Pragma("unroll")                                                           \
    for (int n = 0; n < 4; ++n)                                                 \
      bfr[n] = __builtin_shufflevector(blo[n], bhi[n], 0, 1, 2, 3, 4, 5, 6, 7); \
    _Pragma("unroll")                                                           \
    for (int m = 0; m < 4; ++m) {                                               \
      i32x8 afr = __builtin_shufflevector(AC[2 * m], AC[2 * m + 1],             \
                                          0, 1, 2, 3, 4, 5, 6, 7);              \
      const u32* spp = (const u32*)&AsB[(KT) * 256 + (wrb + m * 16 + q4 * 4) * 2]; \
      u32 sp0 = spp[0], sp1 = spp[1];                                           \
      f32x4 sa;                                                                 \
      sa.x = __uint_as_float(sp0 << 16);                                        \
      sa.y = __uint_as_float(sp0 & 0xFFFF0000u);                                \
      sa.z = __uint_as_float(sp1 << 16);                                        \
      sa.w = __uint_as_float(sp1 & 0xFFFF0000u);                                \
      const f32x4 s = sa * wsb;                                                 \
      f32x4 acc[4];                                                             \
      __builtin_amdgcn_s_setprio(1);                                            \
      _Pragma("unroll")                                                         \
      for (int n = 0; n < 4; ++n)                                               \
        acc[n] = __builtin_amdgcn_mfma_scale_f32_16x16x128_f8f6f4(              \
            afr, bfr[n], z4, 0, 0, 0, 0x7F7F7F7F, 0, 0x7F7F7F7F);               \
      __builtin_amdgcn_s_setprio(0);                                            \
      _Pragma("unroll")                                                         \
      for (int n = 0; n < 4; ++n) accm[m][n] += acc[n] * s;                     \
    }                                                                           \
  } while (0)

#pragma unroll 1
  for (int kt2 = 0; kt2 < 16; ++kt2) {
    BODY(kt2 * 2,     aA, aB);
    BODY(kt2 * 2 + 1, aB, aA);
  }
#undef BODY
#undef APREF
#undef BSTAGE

#pragma unroll
  for (int m = 0; m < 4; ++m) {
#pragma unroll
    for (int r = 0; r < 4; ++r) {
      float* Cp = C + (size_t)(brow + wrb + m * 16 + q4 * 4 + r) * HDIM + bcol + wcb + r16;
#pragma unroll
      for (int n = 0; n < 4; ++n) Cp[n * 16] = accm[m][n][r];
    }
  }
}

extern "C" void kernel_launch(void* const* d_in, const int* in_sizes, int n_in,
                              void* d_out, int out_size, void* d_ws, size_t ws_size,
                              hipStream_t stream) {
  const float* x  = (const float*)d_in[0];
  const float* nw = (const float*)d_in[1];
  const float* w0 = (const float*)d_in[2];
  const float* w1 = (const float*)d_in[3];
  const float* w2 = (const float*)d_in[4];
  const float* s0 = (const float*)d_in[5];
  const float* s1 = (const float*)d_in[6];
  const float* s2 = (const float*)d_in[7];
  float* out = (float*)d_out;
  char* ws = (char*)d_ws;

  u8*  wqt   = (u8*)ws;                               // 3 x 16MB
  u32* q     = (u32*)(ws + (size_t)48 * MBYTE);       // 64MB fp8 activations
  u16* asc   = (u16*)(ws + (size_t)112 * MBYTE);      // 1MB  [32][T] bf16
  float* rsd = (float*)(ws + (size_t)114 * MBYTE);    // 256MB residual

  k_wconv<<<dim3(64, 64, 3), 256, 0, stream>>>(w0, w1, w2, wqt);

  k_norm<0><<<TTOK, 256, 0, stream>>>(x, rsd, nw, q, asc, nullptr);
  k_gemm<<<4096, 256, 0, stream>>>((const u8*)q, wqt, asc, s0, out);

  k_norm<1><<<TTOK, 256, 0, stream>>>(out, rsd, nw + HDIM, q, asc, nullptr);
  k_gemm<<<4096, 256, 0, stream>>>((const u8*)q, wqt + (size_t)16 * MBYTE, asc, s1, out);

  k_norm<1><<<TTOK, 256, 0, stream>>>(out, rsd, nw + 2 * HDIM, q, asc, nullptr);
  k_gemm<<<4096, 256, 0, stream>>>((const u8*)q, wqt + (size_t)32 * MBYTE, asc, s2, out);

  k_norm<2><<<TTOK, 256, 0, stream>>>(out, rsd, nw + 3 * HDIM, nullptr, nullptr, out);
}

// Round 13
// 2717.259 us; speedup vs baseline: 1.2333x; 1.0749x over previous
//
#include <hip/hip_runtime.h>

typedef __attribute__((ext_vector_type(4))) float f32x4;
typedef __attribute__((ext_vector_type(4))) unsigned int u32x4;
typedef __attribute__((ext_vector_type(4))) int i32x4;
typedef __attribute__((ext_vector_type(8))) int i32x8;
typedef unsigned char u8;
typedef unsigned short u16;
typedef unsigned int u32;

#define MBYTE (1024*1024)
#define TTOK 16384
#define HDIM 4096

// Interleaved operand layout (A and B both produced by our kernels):
// row-major 4096B rows of 32 K-tiles x 128B; within a tile, chunk c = p*4+q4
// (16B) holds lane (.,q4)'s fragment bytes for half p. K-permutation identical
// for A and B -> any self-consistent HW K-mapping gives the same dot product
// (HW scales fed as 1.0).

__device__ __forceinline__ void gload_lds16(const void* g, void* l) {
  __builtin_amdgcn_global_load_lds((const __attribute__((address_space(1))) void*)g,
                                   (__attribute__((address_space(3))) void*)l, 16, 0, 0);
}

// ---- weight convert + transpose: W[k][n] f32 -> WT[n][k-interleaved] fp8 ----
__global__ __launch_bounds__(256) void k_wconv(const float* __restrict__ w0,
                                               const float* __restrict__ w1,
                                               const float* __restrict__ w2,
                                               u8* __restrict__ out) {
  __shared__ float tl[64][68];
  const int tid = threadIdx.x;
  const int bn = blockIdx.x, bk = blockIdx.y, z = blockIdx.z;
  const float* W = (z == 0) ? w0 : (z == 1 ? w1 : w2);
  u8* o = out + (size_t)z * 16 * MBYTE;
#pragma unroll
  for (int it = 0; it < 4; ++it) {
    int idx = it * 256 + tid;
    int r = idx >> 4, c4 = idx & 15;
    f32x4 v = *(const f32x4*)(W + (size_t)(bk * 64 + r) * HDIM + bn * 64 + c4 * 4);
    *(f32x4*)&tl[r][c4 * 4] = v;
  }
  __syncthreads();
  {
    int n = tid >> 2, q4 = tid & 3;
    u32 dw[4];
#pragma unroll
    for (int d = 0; d < 4; ++d) {
      int k0 = (d >> 1) * 32 + q4 * 8 + (d & 1) * 4;
      int w = __builtin_amdgcn_cvt_pk_fp8_f32(tl[k0 + 0][n], tl[k0 + 1][n], 0, false);
      w = __builtin_amdgcn_cvt_pk_fp8_f32(tl[k0 + 2][n], tl[k0 + 3][n], w, true);
      dw[d] = (u32)w;
    }
    u32x4 pack = {dw[0], dw[1], dw[2], dw[3]};
    *(u32x4*)(o + (size_t)(bn * 64 + n) * HDIM + (bk >> 1) * 128 + (bk & 1) * 64 + q4 * 16) = pack;
  }
}

// ---- fused elementwise: MODE 0: relu+rms+quant; 1: add+rms+quant; 2: add+rms->yout ----
// Group scale is rounded to bf16 FIRST, then used for quantization -> GEMM's
// bf16 dequant scale cancels exactly.
template <int MODE>
__global__ __launch_bounds__(256) void k_norm(const float* __restrict__ in,
                                              float* __restrict__ resid,
                                              const float* __restrict__ nw,
                                              u32* __restrict__ qout,
                                              u16* __restrict__ asct,
                                              float* __restrict__ yout) {
  const int row = blockIdx.x, t = threadIdx.x;
  const size_t base = (size_t)row * HDIM;
  const f32x4* inr = (const f32x4*)(in + base);
  f32x4* residr = (f32x4*)(resid + base);
  f32x4 v[4];
  float ss = 0.f;
#pragma unroll
  for (int j = 0; j < 4; ++j) {
    f32x4 a = inr[j * 256 + t];
    if (MODE == 0) {
      a.x = fmaxf(a.x, 0.f); a.y = fmaxf(a.y, 0.f);
      a.z = fmaxf(a.z, 0.f); a.w = fmaxf(a.w, 0.f);
    } else {
      f32x4 rz = residr[j * 256 + t];
      a.x += rz.x; a.y += rz.y; a.z += rz.z; a.w += rz.w;
    }
    if (MODE < 2) residr[j * 256 + t] = a;
    v[j] = a;
    ss += a.x * a.x + a.y * a.y + a.z * a.z + a.w * a.w;
  }
#pragma unroll
  for (int m = 1; m <= 32; m <<= 1) ss += __shfl_xor(ss, m, 64);
  __shared__ float sred[4];
  if ((t & 63) == 0) sred[t >> 6] = ss;
  __syncthreads();
  float tot = sred[0] + sred[1] + sred[2] + sred[3];
  float rinv = rsqrtf(tot * (1.f / (float)HDIM) + 1e-6f);
#pragma unroll
  for (int j = 0; j < 4; ++j) {
    f32x4 nv = ((const f32x4*)nw)[j * 256 + t];
    f32x4 y;
    y.x = v[j].x * rinv * nv.x; y.y = v[j].y * rinv * nv.y;
    y.z = v[j].z * rinv * nv.z; y.w = v[j].w * rinv * nv.w;
    if (MODE == 2) {
      ((f32x4*)yout)[(size_t)row * 1024 + j * 256 + t] = y;
    } else {
      float am = fmaxf(fmaxf(fabsf(y.x), fabsf(y.y)), fmaxf(fabsf(y.z), fabsf(y.w)));
#pragma unroll
      for (int m = 1; m <= 16; m <<= 1) am = fmaxf(am, __shfl_xor(am, m, 64));
      am = fmaxf(am, 1e-12f);
      float s = am * (1.f / 448.f);
      u32 x = __float_as_uint(s);
      u32 rb = (x + 0x7FFFu + ((x >> 16) & 1u)) >> 16;     // RNE to bf16
      float sbf = __uint_as_float(rb << 16);
      float inv = 1.0f / sbf;
      int d = __builtin_amdgcn_cvt_pk_fp8_f32(y.x * inv, y.y * inv, 0, false);
      d = __builtin_amdgcn_cvt_pk_fp8_f32(y.z * inv, y.w * inv, d, true);
      int k4 = j * 256 + t;
      int k4w = k4 & 31;
      int k4n = (k4 & ~31) | (((k4w >> 4) & 1) << 4) | (((k4w >> 1) & 3) << 2)
              | (((k4w >> 3) & 1) << 1) | (k4w & 1);
      qout[(size_t)row * 1024 + k4n] = (u32)d;
      if ((t & 31) == 0) asct[(size_t)(j * 8 + (t >> 5)) * TTOK + row] = (u16)rb;
    }
  }
}

// ---- fp8 block-scaled GEMM, 128x128 tile, 4 waves (64x64), BK=128, MX-rate MFMA.
// B via LDS (3 buffers, swizzled gload_lds, prefetch distance 2); A-fragments
// DIRECT from global into regs (SINGLE-buffered aA, loaded at body top, L1/L2-
// served, coalesced 64B segments). ONE s_barrier per kt; counted vmcnt(4) at
// top retires BSTAGE(kt) (2-body lead) and leaves BSTAGE(kt+1) in flight;
// A-load waits are compiler dependency-tracked.
__global__ __launch_bounds__(256, 2)
void k_gemm(const u8* __restrict__ A,     // [T][4096] fp8 interleaved
            const u8* __restrict__ B,     // [4096][4096] fp8 interleaved
            const u16* __restrict__ aSb,  // [32][T] bf16 scales
            const float* __restrict__ bS, // [32][32]
            float* __restrict__ C) {      // [T][4096]
  __shared__ u8 Bl[3][128 * 128];   // 48KB
  __shared__ u8 AsB[32 * 128 * 2];  // 8KB bf16 act scales [kt][row]
  const int tid = threadIdx.x;
  const int lane = tid & 63, wave = tid >> 6;
  // bijective XCD swizzle: 4096 blocks, 8 XCDs, 512 per chunk (bn fast -> A-panel L2 reuse)
  const int lin = blockIdx.x;
  const int swzb = (lin & 7) * 512 + (lin >> 3);
  const int bn = swzb & 31, bm = swzb >> 5;
  const int brow = bm * 128, bcol = bn * 128;
  const int wrb = (wave >> 1) * 64, wcb = (wave & 1) * 64;   // 64x64 wave tile
  const int r16 = lane & 15, q4 = lane >> 4;
  const int swz3 = r16 & 7;
  const int c0 = (q4 ^ swz3) << 4;
  const int c1 = ((4 + q4) ^ swz3) << 4;

  // B staging: pass i covers rows i*32 + (tid>>3), chunk (tid&7), inverse-swizzled src
  const int srow = tid >> 3;
  const int sc = ((tid & 7) ^ (srow & 7)) << 4;
  const u8* bP = B + (size_t)(bcol + srow) * HDIM + sc;
  const int ldst = tid * 16;

#define BSTAGE(bi, kt) do {                                                     \
    _Pragma("unroll")                                                           \
    for (int i = 0; i < 4; ++i)                                                 \
      gload_lds16(bP + (size_t)(kt) * 128 + (size_t)i * 32 * HDIM,              \
                  &Bl[bi][i * 4096 + ldst]);                                    \
  } while (0)

  // A direct-fragment base: lane (r16,q4), row-block m -> raw chunks q4*16, +64
  const u8* aD = A + (size_t)(brow + wrb + r16) * HDIM + q4 * 16;

  // prologue: As FIRST (oldest in FIFO), then B0, B1
  {
    const u8* asrc = (const u8*)aSb;
#pragma unroll
    for (int j = 0; j < 2; ++j) {
      int ch = j * 256 + tid;
      gload_lds16(asrc + (size_t)(ch >> 4) * (TTOK * 2) + (size_t)brow * 2 + (ch & 15) * 16,
                  &AsB[j * 4096 + ldst]);
    }
  }
  BSTAGE(0, 0);
  BSTAGE(1, 1);

  f32x4 accm[4][4] = {};
  const f32x4 z4 = {0.f, 0.f, 0.f, 0.f};
  int cur = 0, s2 = 2;

#pragma unroll 1
  for (int kt = 0; kt < 32; ++kt) {
    // retire BSTAGE(kt) (+As at kt=0); leave BSTAGE(kt+1) in flight
    if (kt < 31) asm volatile("s_waitcnt vmcnt(4)" ::: "memory");
    else         asm volatile("s_waitcnt vmcnt(0)" ::: "memory");
    __builtin_amdgcn_s_barrier();
    __builtin_amdgcn_sched_barrier(0);   // nothing hoists above the barrier

    // A fragments for this kt: 8 coalesced dwordx4 from global (L1/L2)
    i32x4 aA[8];
#pragma unroll
    for (int m = 0; m < 4; ++m) {
      const u8* p_ = aD + (size_t)m * 16 * HDIM + (size_t)kt * 128;
      aA[2 * m]     = *(const i32x4*)(p_);
      aA[2 * m + 1] = *(const i32x4*)(p_ + 64);
    }

    const u8* BlC = &Bl[cur][0];
    i32x4 blo[4], bhi[4];
#pragma unroll
    for (int n = 0; n < 4; ++n) {
      const u8* rp = BlC + (wcb + n * 16 + r16) * 128;
      blo[n] = *(const i32x4*)(rp + c0);
      bhi[n] = *(const i32x4*)(rp + c1);
    }

    if (kt < 30) BSTAGE(s2, kt + 2);     // prefetch distance 2

    const float wsb = bS[kt * 32 + bn];  // wave-uniform -> SMEM
    i32x8 bfr[4];
#pragma unroll
    for (int n = 0; n < 4; ++n)
      bfr[n] = __builtin_shufflevector(blo[n], bhi[n], 0, 1, 2, 3, 4, 5, 6, 7);

#pragma unroll
    for (int m = 0; m < 4; ++m) {
      i32x8 afr = __builtin_shufflevector(aA[2 * m], aA[2 * m + 1],
                                          0, 1, 2, 3, 4, 5, 6, 7);
      const u32* spp = (const u32*)&AsB[kt * 256 + (wrb + m * 16 + q4 * 4) * 2];
      u32 sp0 = spp[0], sp1 = spp[1];
      f32x4 sa;
      sa.x = __uint_as_float(sp0 << 16);
      sa.y = __uint_as_float(sp0 & 0xFFFF0000u);
      sa.z = __uint_as_float(sp1 << 16);
      sa.w = __uint_as_float(sp1 & 0xFFFF0000u);
      const f32x4 s = sa * wsb;
      f32x4 acc[4];
      __builtin_amdgcn_s_setprio(1);
#pragma unroll
      for (int n = 0; n < 4; ++n)
        acc[n] = __builtin_amdgcn_mfma_scale_f32_16x16x128_f8f6f4(
            afr, bfr[n], z4, 0, 0, 0, 0x7F7F7F7F, 0, 0x7F7F7F7F);
      __builtin_amdgcn_s_setprio(0);
#pragma unroll
      for (int n = 0; n < 4; ++n) accm[m][n] += acc[n] * s;
    }

    cur = (cur == 2) ? 0 : cur + 1;
    s2  = (s2 == 2) ? 0 : s2 + 1;
  }
#undef BSTAGE

#pragma unroll
  for (int m = 0; m < 4; ++m) {
#pragma unroll
    for (int r = 0; r < 4; ++r) {
      float* Cp = C + (size_t)(brow + wrb + m * 16 + q4 * 4 + r) * HDIM + bcol + wcb + r16;
#pragma unroll
      for (int n = 0; n < 4; ++n) Cp[n * 16] = accm[m][n][r];
    }
  }
}

extern "C" void kernel_launch(void* const* d_in, const int* in_sizes, int n_in,
                              void* d_out, int out_size, void* d_ws, size_t ws_size,
                              hipStream_t stream) {
  const float* x  = (const float*)d_in[0];
  const float* nw = (const float*)d_in[1];
  const float* w0 = (const float*)d_in[2];
  const float* w1 = (const float*)d_in[3];
  const float* w2 = (const float*)d_in[4];
  const float* s0 = (const float*)d_in[5];
  const float* s1 = (const float*)d_in[6];
  const float* s2 = (const float*)d_in[7];
  float* out = (float*)d_out;
  char* ws = (char*)d_ws;

  u8*  wqt   = (u8*)ws;                               // 3 x 16MB
  u32* q     = (u32*)(ws + (size_t)48 * MBYTE);       // 64MB fp8 activations
  u16* asc   = (u16*)(ws + (size_t)112 * MBYTE);      // 1MB  [32][T] bf16
  float* rsd = (float*)(ws + (size_t)114 * MBYTE);    // 256MB residual

  k_wconv<<<dim3(64, 64, 3), 256, 0, stream>>>(w0, w1, w2, wqt);

  k_norm<0><<<TTOK, 256, 0, stream>>>(x, rsd, nw, q, asc, nullptr);
  k_gemm<<<4096, 256, 0, stream>>>((const u8*)q, wqt, asc, s0, out);

  k_norm<1><<<TTOK, 256, 0, stream>>>(out, rsd, nw + HDIM, q, asc, nullptr);
  k_gemm<<<4096, 256, 0, stream>>>((const u8*)q, wqt + (size_t)16 * MBYTE, asc, s1, out);

  k_norm<1><<<TTOK, 256, 0, stream>>>(out, rsd, nw + 2 * HDIM, q, asc, nullptr);
  k_gemm<<<4096, 256, 0, stream>>>((const u8*)q, wqt + (size_t)32 * MBYTE, asc, s2, out);

  k_norm<2><<<TTOK, 256, 0, stream>>>(out, rsd, nw + 3 * HDIM, nullptr, nullptr, out);
}

// Round 14
// 1626.790 us; speedup vs baseline: 2.0600x; 1.6703x over previous
//
#include <hip/hip_runtime.h>

typedef __attribute__((ext_vector_type(4))) float f32x4;
typedef __attribute__((ext_vector_type(4))) unsigned int u32x4;
typedef __attribute__((ext_vector_type(4))) int i32x4;
typedef __attribute__((ext_vector_type(8))) int i32x8;
typedef unsigned char u8;
typedef unsigned int u32;

#define MBYTE (1024*1024)
#define TTOK 16384
#define HDIM 4096

// Interleaved operand layout (A and B both produced by our kernels):
// row-major 4096B rows of 32 K-tiles x 128B; within a tile, chunk c = p*4+q4
// (16B) holds lane (.,q4)'s fragment bytes for half p. K-permutation identical
// for A and B -> any self-consistent HW K-mapping gives the same dot product
// (HW scales fed as 1.0).

__device__ __forceinline__ void gload_lds16(const void* g, void* l) {
  __builtin_amdgcn_global_load_lds((const __attribute__((address_space(1))) void*)g,
                                   (__attribute__((address_space(3))) void*)l, 16, 0, 0);
}

// ---- weight convert + transpose: W[k][n] f32 -> WT[n][k-interleaved] fp8 ----
__global__ __launch_bounds__(256) void k_wconv(const float* __restrict__ w0,
                                               const float* __restrict__ w1,
                                               const float* __restrict__ w2,
                                               u8* __restrict__ out) {
  __shared__ float tl[64][68];
  const int tid = threadIdx.x;
  const int bn = blockIdx.x, bk = blockIdx.y, z = blockIdx.z;
  const float* W = (z == 0) ? w0 : (z == 1 ? w1 : w2);
  u8* o = out + (size_t)z * 16 * MBYTE;
#pragma unroll
  for (int it = 0; it < 4; ++it) {
    int idx = it * 256 + tid;
    int r = idx >> 4, c4 = idx & 15;
    f32x4 v = *(const f32x4*)(W + (size_t)(bk * 64 + r) * HDIM + bn * 64 + c4 * 4);
    *(f32x4*)&tl[r][c4 * 4] = v;
  }
  __syncthreads();
  {
    int n = tid >> 2, q4 = tid & 3;
    u32 dw[4];
#pragma unroll
    for (int d = 0; d < 4; ++d) {
      int k0 = (d >> 1) * 32 + q4 * 8 + (d & 1) * 4;
      int w = __builtin_amdgcn_cvt_pk_fp8_f32(tl[k0 + 0][n], tl[k0 + 1][n], 0, false);
      w = __builtin_amdgcn_cvt_pk_fp8_f32(tl[k0 + 2][n], tl[k0 + 3][n], w, true);
      dw[d] = (u32)w;
    }
    u32x4 pack = {dw[0], dw[1], dw[2], dw[3]};
    *(u32x4*)(o + (size_t)(bn * 64 + n) * HDIM + (bk >> 1) * 128 + (bk & 1) * 64 + q4 * 16) = pack;
  }
}

// ---- fused elementwise: MODE 0: relu+rms+quant; 1: add+rms+quant; 2: add+rms->yout ----
template <int MODE>
__global__ __launch_bounds__(256) void k_norm(const float* __restrict__ in,
                                              float* __restrict__ resid,
                                              const float* __restrict__ nw,
                                              u32* __restrict__ qout,
                                              float* __restrict__ asct,
                                              float* __restrict__ yout) {
  const int row = blockIdx.x, t = threadIdx.x;
  const size_t base = (size_t)row * HDIM;
  const f32x4* inr = (const f32x4*)(in + base);
  f32x4* residr = (f32x4*)(resid + base);
  f32x4 v[4];
  float ss = 0.f;
#pragma unroll
  for (int j = 0; j < 4; ++j) {
    f32x4 a = inr[j * 256 + t];
    if (MODE == 0) {
      a.x = fmaxf(a.x, 0.f); a.y = fmaxf(a.y, 0.f);
      a.z = fmaxf(a.z, 0.f); a.w = fmaxf(a.w, 0.f);
    } else {
      f32x4 rz = residr[j * 256 + t];
      a.x += rz.x; a.y += rz.y; a.z += rz.z; a.w += rz.w;
    }
    if (MODE < 2) residr[j * 256 + t] = a;
    v[j] = a;
    ss += a.x * a.x + a.y * a.y + a.z * a.z + a.w * a.w;
  }
#pragma unroll
  for (int m = 1; m <= 32; m <<= 1) ss += __shfl_xor(ss, m, 64);
  __shared__ float sred[4];
  if ((t & 63) == 0) sred[t >> 6] = ss;
  __syncthreads();
  float tot = sred[0] + sred[1] + sred[2] + sred[3];
  float rinv = rsqrtf(tot * (1.f / (float)HDIM) + 1e-6f);
#pragma unroll
  for (int j = 0; j < 4; ++j) {
    f32x4 nv = ((const f32x4*)nw)[j * 256 + t];
    f32x4 y;
    y.x = v[j].x * rinv * nv.x; y.y = v[j].y * rinv * nv.y;
    y.z = v[j].z * rinv * nv.z; y.w = v[j].w * rinv * nv.w;
    if (MODE == 2) {
      ((f32x4*)yout)[(size_t)row * 1024 + j * 256 + t] = y;
    } else {
      float am = fmaxf(fmaxf(fabsf(y.x), fabsf(y.y)), fmaxf(fabsf(y.z), fabsf(y.w)));
#pragma unroll
      for (int m = 1; m <= 16; m <<= 1) am = fmaxf(am, __shfl_xor(am, m, 64));
      am = fmaxf(am, 1e-12f);
      float scale = am / 448.f;
      float inv = 448.f / am;
      int d = __builtin_amdgcn_cvt_pk_fp8_f32(y.x * inv, y.y * inv, 0, false);
      d = __builtin_amdgcn_cvt_pk_fp8_f32(y.z * inv, y.w * inv, d, true);
      // interleaved layout: permute u32 index within each 32-u32 (128B) K-tile
      int k4 = j * 256 + t;
      int k4w = k4 & 31;
      int k4n = (k4 & ~31) | (((k4w >> 4) & 1) << 4) | (((k4w >> 1) & 3) << 2)
              | (((k4w >> 3) & 1) << 1) | (k4w & 1);
      qout[(size_t)row * 1024 + k4n] = (u32)d;
      if ((t & 31) == 0) asct[(size_t)(j * 8 + (t >> 5)) * TTOK + row] = scale;
    }
  }
}

// ---- fp8 block-scaled GEMM, 128x128 tile, 4 waves of 64x64, BK=128, MX-rate MFMA.
// R9 structure (champion): A+B dbuf LDS, As f32 in LDS, clean counted vmcnt(8),
// 2 barriers/kt, setprio. ONE change vs R9: supertile block mapping (2bm x 4bn
// per 8-block group within each XCD chunk) so concurrent blocks share ~3MB of
// A+B panels (fits 4MB per-XCD L2) instead of touching all 16MB of B.
__global__ __launch_bounds__(256, 2) void k_gemm(const u8* __restrict__ A,    // [T][4096] fp8 interleaved
                                                 const u8* __restrict__ B,    // [4096][4096] fp8 interleaved
                                                 const float* __restrict__ aS, // [32][T]
                                                 const float* __restrict__ bS, // [32][32]
                                                 float* __restrict__ C) {      // [T][4096]
  __shared__ u8 Al[2][128 * 128];
  __shared__ u8 Bl[2][128 * 128];
  __shared__ float As[32 * 128];        // per-block activation scales [kt][row]
  const int tid = threadIdx.x;
  const int lane = tid & 63, wave = tid >> 6;
  // XCD chunk (bijective: 4096 blocks, 8 XCDs, 512/chunk) + 2bm x 4bn supertiles
  const int lin = blockIdx.x;
  const int xcd = lin & 7, tt = lin >> 3;
  const int sidx = tt >> 3, rr = tt & 7;        // 64 supertiles of 8 blocks
  const int sm = sidx >> 3, sn = sidx & 7;      // supertile coords (8 x 8)
  const int bm = xcd * 16 + sm * 2 + (rr >> 2); // 16 bm rows per XCD
  const int bn = sn * 4 + (rr & 3);
  const int brow = bm * 128, bcol = bn * 128;
  const int wrb = (wave >> 1) * 64, wcb = (wave & 1) * 64;   // 64x64 wave tile
  const int r16 = lane & 15, q4 = lane >> 4;
  const int swz3 = r16 & 7;
  const int c0 = (q4 ^ swz3) << 4;        // p=0 chunk for this lane
  const int c1 = ((4 + q4) ^ swz3) << 4;  // p=1 chunk

  // staging (256 thr): pass i covers rows i*32 + (tid>>3), chunk (tid&7), inverse-swizzled
  const int srow = tid >> 3;
  const int scol = (((tid & 7) ^ (srow & 7)) << 4);
  const u8* aP = A + (size_t)(brow + srow) * HDIM + scol;
  const u8* bP = B + (size_t)(bcol + srow) * HDIM + scol;
  const int ldst = tid * 16;

  // STAGE = 8 vmem instructions per wave (4 A + 4 B), 32KB total
#define STAGE(c, kt) do {                                                       \
    _Pragma("unroll")                                                           \
    for (int i = 0; i < 4; ++i) {                                               \
      gload_lds16(aP + (size_t)(kt) * 128 + (size_t)i * 32 * HDIM,              \
                  &Al[c][i * 4096 + ldst]);                                     \
      gload_lds16(bP + (size_t)(kt) * 128 + (size_t)i * 32 * HDIM,              \
                  &Bl[c][i * 4096 + ldst]);                                     \
    }                                                                           \
  } while (0)

  // prologue: load aS slice to regs, start stages, park aS into LDS
  f32x4 av[4];
#pragma unroll
  for (int i = 0; i < 4; ++i) {
    const int kt_ = i * 8 + (tid >> 5);
    const int r_ = (tid & 31) * 4;
    av[i] = *(const f32x4*)(aS + (size_t)kt_ * TTOK + brow + r_);
  }
  STAGE(0, 0);
  STAGE(1, 1);                                   // FIFO: 4 aS + 16 stage
  asm volatile("s_waitcnt vmcnt(16)" ::: "memory");   // aS loads retired
#pragma unroll
  for (int i = 0; i < 4; ++i)
    *(f32x4*)&As[i * 1024 + tid * 4] = av[i];
  asm volatile("s_waitcnt lgkmcnt(0)" ::: "memory");  // As visible after barrier

  f32x4 accm[4][4] = {};
  const f32x4 z4 = {0.f, 0.f, 0.f, 0.f};

#pragma unroll 1
  for (int kt = 0; kt < 32; ++kt) {
    const int cur = kt & 1;
    // tile kt's 8 stage loads are oldest; tile kt+1's 8 stay in flight
    if (kt < 31) asm volatile("s_waitcnt vmcnt(8)" ::: "memory");
    else         asm volatile("s_waitcnt vmcnt(0)" ::: "memory");
    __builtin_amdgcn_s_barrier();
    __builtin_amdgcn_sched_barrier(0);   // nothing hoists above the barrier

    const float wsb = bS[kt * 32 + bn];  // wave-uniform -> SMEM (lgkm), not vmcnt

    i32x8 bfr[4];
#pragma unroll
    for (int n = 0; n < 4; ++n) {
      const u8* rp = &Bl[cur][(wcb + n * 16 + r16) * 128];
      i32x4 lo = *(const i32x4*)(rp + c0);
      i32x4 hi = *(const i32x4*)(rp + c1);
      bfr[n] = __builtin_shufflevector(lo, hi, 0, 1, 2, 3, 4, 5, 6, 7);
    }

#pragma unroll
    for (int m = 0; m < 4; ++m) {
      const u8* rp = &Al[cur][(wrb + m * 16 + r16) * 128];
      i32x4 lo = *(const i32x4*)(rp + c0);
      i32x4 hi = *(const i32x4*)(rp + c1);
      i32x8 afr = __builtin_shufflevector(lo, hi, 0, 1, 2, 3, 4, 5, 6, 7);
      const f32x4 sa = *(const f32x4*)&As[kt * 128 + wrb + m * 16 + q4 * 4];
      const f32x4 s = sa * wsb;
      f32x4 acc[4];
      __builtin_amdgcn_s_setprio(1);
#pragma unroll
      for (int n = 0; n < 4; ++n)
        acc[n] = __builtin_amdgcn_mfma_scale_f32_16x16x128_f8f6f4(
            afr, bfr[n], z4, 0, 0, 0, 0x7F7F7F7F, 0, 0x7F7F7F7F);
      __builtin_amdgcn_s_setprio(0);
#pragma unroll
      for (int n = 0; n < 4; ++n)
        accm[m][n] += acc[n] * s;
    }

    __builtin_amdgcn_sched_barrier(0);   // all buf[cur] reads stay above barrier2
    __builtin_amdgcn_s_barrier();        // all waves done reading buf[cur]
    if (kt < 30) STAGE(cur, kt + 2);     // overwrite buf[cur] with tile kt+2
  }
#undef STAGE

#pragma unroll
  for (int m = 0; m < 4; ++m) {
#pragma unroll
    for (int r = 0; r < 4; ++r) {
      float* Cp = C + (size_t)(brow + wrb + m * 16 + q4 * 4 + r) * HDIM + bcol + wcb + r16;
#pragma unroll
      for (int n = 0; n < 4; ++n) Cp[n * 16] = accm[m][n][r];
    }
  }
}

extern "C" void kernel_launch(void* const* d_in, const int* in_sizes, int n_in,
                              void* d_out, int out_size, void* d_ws, size_t ws_size,
                              hipStream_t stream) {
  const float* x  = (const float*)d_in[0];
  const float* nw = (const float*)d_in[1];
  const float* w0 = (const float*)d_in[2];
  const float* w1 = (const float*)d_in[3];
  const float* w2 = (const float*)d_in[4];
  const float* s0 = (const float*)d_in[5];
  const float* s1 = (const float*)d_in[6];
  const float* s2 = (const float*)d_in[7];
  float* out = (float*)d_out;
  char* ws = (char*)d_ws;

  u8*  wqt   = (u8*)ws;                               // 3 x 16MB
  u32* q     = (u32*)(ws + (size_t)48 * MBYTE);       // 64MB fp8 activations
  float* asc = (float*)(ws + (size_t)112 * MBYTE);    // 2MB  [32][T]
  float* rsd = (float*)(ws + (size_t)114 * MBYTE);    // 256MB residual

  k_wconv<<<dim3(64, 64, 3), 256, 0, stream>>>(w0, w1, w2, wqt);

  k_norm<0><<<TTOK, 256, 0, stream>>>(x, rsd, nw, q, asc, nullptr);
  k_gemm<<<4096, 256, 0, stream>>>((const u8*)q, wqt, asc, s0, out);

  k_norm<1><<<TTOK, 256, 0, stream>>>(out, rsd, nw + HDIM, q, asc, nullptr);
  k_gemm<<<4096, 256, 0, stream>>>((const u8*)q, wqt + (size_t)16 * MBYTE, asc, s1, out);

  k_norm<1><<<TTOK, 256, 0, stream>>>(out, rsd, nw + 2 * HDIM, q, asc, nullptr);
  k_gemm<<<4096, 256, 0, stream>>>((const u8*)q, wqt + (size_t)32 * MBYTE, asc, s2, out);

  k_norm<2><<<TTOK, 256, 0, stream>>>(out, rsd, nw + 3 * HDIM, nullptr, nullptr, out);
}